// Round 3
// baseline (98.673 us; speedup 1.0000x reference)
//
#include <hip/hip_runtime.h>
#include <hip/hip_bf16.h>

#define B_ 4
#define T_ 800
#define U_ 150
#define D_ 512
#define H_ 256
#define PADH2 132   // 132 % 32 == 4 -> worst LDS aliasing 2-way (free)

static constexpr float ARG_SCALE = 2.8853900817779268f; // 2/ln(2): tanh(x)=1-2/(1+2^(c*x))
static constexpr float LOG2E_F   = 1.4426950408889634f;

extern "C" __device__ float __ocml_exp2_f32(float);

__device__ __forceinline__ float fast_exp2(float x) {
#if __has_builtin(__builtin_amdgcn_exp2f)
    return __builtin_amdgcn_exp2f(x);   // v_exp_f32
#else
    return __ocml_exp2_f32(x);
#endif
}
__device__ __forceinline__ float fast_rcp(float x) {
#if __has_builtin(__builtin_amdgcn_rcpf)
    return __builtin_amdgcn_rcpf(x);    // v_rcp_f32
#else
    return 1.0f / x;
#endif
}

__device__ __forceinline__ float4 fma4(float4 w, float x, float4 a) {
    a.x = fmaf(w.x, x, a.x); a.y = fmaf(w.y, x, a.y);
    a.z = fmaf(w.z, x, a.z); a.w = fmaf(w.w, x, a.w);
    return a;
}

// ---------------------------------------------------------------------------
// K1 v3: projections with split-K. 1900 blocks:
//   blk 0..1599 : enc  -> (chunk 0..399) x (hh 0..1) x (ep 0..1)
//   blk 1600..1899 : dec -> (chunk 0..74) x (hh 0..1) x (ep 0..1)
// Block = 8 rows x 128 h-cols x 256 e-range. Thread = 1 row x 4 h.
// Writes RAW partial dot products (no bias/scale) to pe{ep}/pd{ep}.
// Grid 1900 -> ~7.4 blocks/CU; LDS 8 KB -> occupancy-friendly.
// ---------------------------------------------------------------------------
__global__ __launch_bounds__(256) void proj_kernel(
    const float* __restrict__ enc, const float* __restrict__ dec,
    const float* __restrict__ W_enc, const float* __restrict__ W_dec,
    float* __restrict__ pe0, float* __restrict__ pe1,
    float* __restrict__ pd0, float* __restrict__ pd1)
{
    const int tid = threadIdx.x;
    int blk = blockIdx.x;
    const float* in; const float* Wm; float* outp;
    if (blk < 1600) {
        in = enc; Wm = W_enc;
        outp = (blk & 1) ? pe1 : pe0;
    } else {
        blk -= 1600;
        in = dec; Wm = W_dec;
        outp = (blk & 1) ? pd1 : pd0;
    }
    const int ep    = blk & 1;
    const int hh    = (blk >> 1) & 1;
    const int chunk = blk >> 2;
    const int row0  = chunk * 8;

    __shared__ float ilds[8][256];   // 8 rows x 256-e slice, 8 KB
    #pragma unroll
    for (int k = 0; k < 2; ++k) {
        int idx = tid + 256 * k;
        int row = idx >> 6, c4 = idx & 63;
        *(float4*)&ilds[row][c4 * 4] =
            ((const float4*)(in + (size_t)(row0 + row) * D_ + ep * 256))[c4];
    }
    __syncthreads();

    const int h4 = tid & 31;       // 4-h group within the 128-h half
    const int rg = tid >> 5;       // row 0..7
    const int hbase = hh * 128 + 4 * h4;

    const float* wbase = Wm + (size_t)(ep * 256) * H_ + hbase;
    const float* ip = &ilds[rg][0];

    float4 a = {0.f, 0.f, 0.f, 0.f};
    #pragma unroll 4
    for (int e = 0; e < 256; e += 2) {
        float4 w0 = *(const float4*)(wbase + (size_t)e * H_);
        float4 w1 = *(const float4*)(wbase + (size_t)(e + 1) * H_);
        float2 x  = *(const float2*)(ip + e);     // wave-broadcast LDS read
        a = fma4(w0, x.x, a);
        a = fma4(w1, x.y, a);
    }
    *(float4*)(outp + (size_t)(row0 + rg) * H_ + hbase) = a;
}

// ---------------------------------------------------------------------------
// K2 v3: partial scores with split-H. Grid (x: ut 0..4 | hs 0..1, y: tt, z: b)
// Block = 32t x 32u tile over a 128-h half; thread (ty,tx) owns 2t x 2u.
// Staging fuses the proj combine: eld = c*(pe0+pe1+b_enc), dld likewise.
// w_score read as UNIFORM global loads (scalar path) - no LDS op.
// sc{hs}[t,u] = sum_{h in half} w[h]*sigmoid; softmax combines halves.
// ---------------------------------------------------------------------------
__global__ __launch_bounds__(256) void score_kernel(
    const float* __restrict__ pe0, const float* __restrict__ pe1,
    const float* __restrict__ pd0, const float* __restrict__ pd1,
    const float* __restrict__ b_enc, const float* __restrict__ b_dec,
    const float* __restrict__ w_score,
    float* __restrict__ sc0, float* __restrict__ sc1)
{
    const int tid = threadIdx.x;
    const int ut = blockIdx.x % 5, hs = blockIdx.x / 5;
    const int tt = blockIdx.y, b = blockIdx.z;

    __shared__ float eld[32][PADH2];
    __shared__ float dld[32][PADH2];

    const int t0 = tt * 32, u0 = ut * 32;
    const int hoff = hs * 128;
    const float* wp = w_score + hoff;

    #pragma unroll
    for (int k = 0; k < 4; ++k) {
        int idx = tid + 256 * k;
        int row = idx >> 5;        // 0..31
        int f4  = idx & 31;        // 0..31 within the 128-h half

        float4 be = ((const float4*)(b_enc + hoff))[f4];
        size_t ge = (size_t)(b * T_ + t0 + row) * H_ + hoff + 4 * f4;
        float4 e0 = *(const float4*)(pe0 + ge);
        float4 e1 = *(const float4*)(pe1 + ge);
        float4 ev;
        ev.x = ARG_SCALE * (e0.x + e1.x + be.x);
        ev.y = ARG_SCALE * (e0.y + e1.y + be.y);
        ev.z = ARG_SCALE * (e0.z + e1.z + be.z);
        ev.w = ARG_SCALE * (e0.w + e1.w + be.w);
        *(float4*)&eld[row][4 * f4] = ev;

        int du = u0 + row; if (du > U_ - 1) du = U_ - 1;
        float4 bd = ((const float4*)(b_dec + hoff))[f4];
        size_t gd = (size_t)(b * U_ + du) * H_ + hoff + 4 * f4;
        float4 d0 = *(const float4*)(pd0 + gd);
        float4 d1 = *(const float4*)(pd1 + gd);
        float4 dv;
        dv.x = ARG_SCALE * (d0.x + d1.x + bd.x);
        dv.y = ARG_SCALE * (d0.y + d1.y + bd.y);
        dv.z = ARG_SCALE * (d0.z + d1.z + bd.z);
        dv.w = ARG_SCALE * (d0.w + d1.w + bd.w);
        *(float4*)&dld[row][4 * f4] = dv;
    }
    __syncthreads();

    const int tx = tid & 15, ty = tid >> 4;
    const float* e0p = &eld[2 * ty][0];
    const float* e1p = &eld[2 * ty + 1][0];
    const float* d0p = &dld[tx][0];
    const float* d1p = &dld[tx + 16][0];

    float4 z = {0.f, 0.f, 0.f, 0.f};
    float4 acc00 = z, acc01 = z, acc10 = z, acc11 = z;

    #pragma unroll 2
    for (int h4 = 0; h4 < 32; ++h4) {
        float4 ea = *(const float4*)(e0p + 4 * h4);
        float4 eb = *(const float4*)(e1p + 4 * h4);
        float4 da = *(const float4*)(d0p + 4 * h4);
        float4 db = *(const float4*)(d1p + 4 * h4);
        float4 w  = ((const float4*)wp)[h4];       // uniform -> s_load

        acc00.x = fmaf(w.x, fast_rcp(1.f + fast_exp2(ea.x + da.x)), acc00.x);
        acc00.y = fmaf(w.y, fast_rcp(1.f + fast_exp2(ea.y + da.y)), acc00.y);
        acc00.z = fmaf(w.z, fast_rcp(1.f + fast_exp2(ea.z + da.z)), acc00.z);
        acc00.w = fmaf(w.w, fast_rcp(1.f + fast_exp2(ea.w + da.w)), acc00.w);

        acc01.x = fmaf(w.x, fast_rcp(1.f + fast_exp2(ea.x + db.x)), acc01.x);
        acc01.y = fmaf(w.y, fast_rcp(1.f + fast_exp2(ea.y + db.y)), acc01.y);
        acc01.z = fmaf(w.z, fast_rcp(1.f + fast_exp2(ea.z + db.z)), acc01.z);
        acc01.w = fmaf(w.w, fast_rcp(1.f + fast_exp2(ea.w + db.w)), acc01.w);

        acc10.x = fmaf(w.x, fast_rcp(1.f + fast_exp2(eb.x + da.x)), acc10.x);
        acc10.y = fmaf(w.y, fast_rcp(1.f + fast_exp2(eb.y + da.y)), acc10.y);
        acc10.z = fmaf(w.z, fast_rcp(1.f + fast_exp2(eb.z + da.z)), acc10.z);
        acc10.w = fmaf(w.w, fast_rcp(1.f + fast_exp2(eb.w + da.w)), acc10.w);

        acc11.x = fmaf(w.x, fast_rcp(1.f + fast_exp2(eb.x + db.x)), acc11.x);
        acc11.y = fmaf(w.y, fast_rcp(1.f + fast_exp2(eb.y + db.y)), acc11.y);
        acc11.z = fmaf(w.z, fast_rcp(1.f + fast_exp2(eb.z + db.z)), acc11.z);
        acc11.w = fmaf(w.w, fast_rcp(1.f + fast_exp2(eb.w + db.w)), acc11.w);
    }

    const float s00 = (acc00.x + acc00.y) + (acc00.z + acc00.w);
    const float s01 = (acc01.x + acc01.y) + (acc01.z + acc01.w);
    const float s10 = (acc10.x + acc10.y) + (acc10.z + acc10.w);
    const float s11 = (acc11.x + acc11.y) + (acc11.z + acc11.w);

    float* sout = hs ? sc1 : sc0;
    const int ta = t0 + 2 * ty, tb = ta + 1;
    const int ua = u0 + tx, ub = ua + 16;          // ua always < U_
    sout[(size_t)(b * T_ + ta) * U_ + ua] = s00;
    sout[(size_t)(b * T_ + tb) * U_ + ua] = s10;
    if (ub < U_) {
        sout[(size_t)(b * T_ + ta) * U_ + ub] = s01;
        sout[(size_t)(b * T_ + tb) * U_ + ub] = s11;
    }
}

// ---------------------------------------------------------------------------
// K3: softmax over U=150 of z = -2*(sc0+sc1). One wave per row; writes d_out.
// ---------------------------------------------------------------------------
__global__ __launch_bounds__(256) void softmax_kernel(
    const float* __restrict__ sc0, const float* __restrict__ sc1,
    float* __restrict__ out)
{
    const int tid  = threadIdx.x;
    const int wave = tid >> 6, lane = tid & 63;
    const int row  = blockIdx.x * 4 + wave;       // 0..3199
    const size_t base = (size_t)row * U_;

    float z0 = -2.f * (sc0[base + lane]      + sc1[base + lane]);
    float z1 = -2.f * (sc0[base + lane + 64] + sc1[base + lane + 64]);
    const bool v2 = (lane + 128) < U_;
    float z2 = v2 ? -2.f * (sc0[base + lane + 128] + sc1[base + lane + 128])
                  : -INFINITY;

    float m = fmaxf(fmaxf(z0, z1), z2);
    #pragma unroll
    for (int off = 32; off > 0; off >>= 1) m = fmaxf(m, __shfl_xor(m, off));

    float p0 = fast_exp2((z0 - m) * LOG2E_F);
    float p1 = fast_exp2((z1 - m) * LOG2E_F);
    float p2 = v2 ? fast_exp2((z2 - m) * LOG2E_F) : 0.f;

    float s = p0 + p1 + p2;
    #pragma unroll
    for (int off = 32; off > 0; off >>= 1) s += __shfl_xor(s, off);

    const float inv = 1.0f / s;   // IEEE divide for accuracy
    out[base + lane]      = p0 * inv;
    out[base + lane + 64] = p1 * inv;
    if (v2) out[base + lane + 128] = p2 * inv;
}

// ---------------------------------------------------------------------------
extern "C" void kernel_launch(void* const* d_in, const int* in_sizes, int n_in,
                              void* d_out, int out_size, void* d_ws, size_t ws_size,
                              hipStream_t stream) {
    const float* enc     = (const float*)d_in[0];
    const float* dec     = (const float*)d_in[1];
    const float* W_enc   = (const float*)d_in[2];
    const float* b_enc   = (const float*)d_in[3];
    const float* W_dec   = (const float*)d_in[4];
    const float* b_dec   = (const float*)d_in[5];
    const float* w_score = (const float*)d_in[6];
    // d_in[7] = b_score: cancels in softmax, unused.

    float* ws = (float*)d_ws;
    float* pe0 = ws;                    // [3200,256] enc partial, e 0..255
    float* pe1 = pe0 + 819200;          // [3200,256] enc partial, e 256..511
    float* pd0 = pe1 + 819200;          // [600,256]
    float* pd1 = pd0 + 153600;          // [600,256]
    float* sc0 = pd1 + 153600;          // [3200,150] score partial, h 0..127
    float* sc1 = sc0 + 480000;          // [3200,150] score partial, h 128..255
    float* out = (float*)d_out;

    proj_kernel<<<1900, 256, 0, stream>>>(enc, dec, W_enc, W_dec, pe0, pe1, pd0, pd1);
    score_kernel<<<dim3(10, 25, 4), 256, 0, stream>>>(pe0, pe1, pd0, pd1,
                                                      b_enc, b_dec, w_score, sc0, sc1);
    softmax_kernel<<<800, 256, 0, stream>>>(sc0, sc1, out);
}

// Round 4
// 44.465 us; speedup vs baseline: 2.2191x; 2.2191x over previous
//
#include <hip/hip_runtime.h>
#include <hip/hip_bf16.h>

#define B_ 4
#define T_ 800
#define U_ 150
#define D_ 512
#define H_ 256
#define PADH2 132   // 132 % 32 == 4 -> worst LDS aliasing 2-way (free)

static constexpr float ARG_SCALE = 2.8853900817779268f; // 2/ln(2): tanh(x)=1-2/(1+2^(c*x))
static constexpr float LOG2E_F   = 1.4426950408889634f;

extern "C" __device__ float __ocml_exp2_f32(float);

__device__ __forceinline__ float fast_exp2(float x) {
#if __has_builtin(__builtin_amdgcn_exp2f)
    return __builtin_amdgcn_exp2f(x);   // v_exp_f32
#else
    return __ocml_exp2_f32(x);
#endif
}
__device__ __forceinline__ float fast_rcp(float x) {
#if __has_builtin(__builtin_amdgcn_rcpf)
    return __builtin_amdgcn_rcpf(x);    // v_rcp_f32
#else
    return 1.0f / x;
#endif
}

__device__ __forceinline__ float4 fma4(float4 w, float x, float4 a) {
    a.x = fmaf(w.x, x, a.x); a.y = fmaf(w.y, x, a.y);
    a.z = fmaf(w.z, x, a.z); a.w = fmaf(w.w, x, a.w);
    return a;
}

// ---------------------------------------------------------------------------
// K1 v4: fused projection + exp2. Grid 475:
//   blk 0..399: enc rows (8/block) ; blk 400..474: dec rows (8/block, 75*8=600)
// Wave w handles e-quarter [128w, 128w+128) for all 8 rows x 256 h.
//   - weights: dense coalesced float4 vmem (1 KB/wave-instr, 8-row reuse -> L1 ok)
//   - inputs : wave-uniform rows -> scalar s_load path (readfirstlane wave id)
// Waves combine via 32 KB LDS reduce; epilogue applies bias, scale, exp2:
//   out[row,h] = exp2( c * (sum_e in*W + bias) )        (c = 2/ln2)
// ---------------------------------------------------------------------------
__global__ __launch_bounds__(256) void proj_exp_kernel(
    const float* __restrict__ enc, const float* __restrict__ dec,
    const float* __restrict__ W_enc, const float* __restrict__ b_enc,
    const float* __restrict__ W_dec, const float* __restrict__ b_dec,
    float* __restrict__ Ee, float* __restrict__ Ed)
{
    const int tid = threadIdx.x;
    const int blk = blockIdx.x;
    const float* in; const float* Wm; const float* bias; float* outp; int row0;
    if (blk < 400) { in = enc; Wm = W_enc; bias = b_enc; outp = Ee; row0 = blk * 8; }
    else           { in = dec; Wm = W_dec; bias = b_dec; outp = Ed; row0 = (blk - 400) * 8; }

    const int h4  = tid & 63;                                   // 64 h4-lanes = 256 h
    const int wid = __builtin_amdgcn_readfirstlane(tid >> 6);   // wave id, forced uniform
    const int eq  = wid * 128;                                  // e-quarter base

    const float* wp = Wm + (size_t)eq * H_ + 4 * h4;
    const float* ip0 = in + (size_t)(row0 + 0) * D_ + eq;
    const float* ip1 = in + (size_t)(row0 + 1) * D_ + eq;
    const float* ip2 = in + (size_t)(row0 + 2) * D_ + eq;
    const float* ip3 = in + (size_t)(row0 + 3) * D_ + eq;
    const float* ip4 = in + (size_t)(row0 + 4) * D_ + eq;
    const float* ip5 = in + (size_t)(row0 + 5) * D_ + eq;
    const float* ip6 = in + (size_t)(row0 + 6) * D_ + eq;
    const float* ip7 = in + (size_t)(row0 + 7) * D_ + eq;

    float4 acc[8] = {};
    #pragma unroll 2
    for (int e = 0; e < 128; e += 4) {
        float4 w0 = *(const float4*)(wp + (size_t)(e + 0) * H_);
        float4 w1 = *(const float4*)(wp + (size_t)(e + 1) * H_);
        float4 w2 = *(const float4*)(wp + (size_t)(e + 2) * H_);
        float4 w3 = *(const float4*)(wp + (size_t)(e + 3) * H_);
        // uniform addresses -> s_load_dwordx4 (scalar path, broadcast via SGPR)
        float4 x0 = *(const float4*)(ip0 + e);
        float4 x1 = *(const float4*)(ip1 + e);
        float4 x2 = *(const float4*)(ip2 + e);
        float4 x3 = *(const float4*)(ip3 + e);
        float4 x4 = *(const float4*)(ip4 + e);
        float4 x5 = *(const float4*)(ip5 + e);
        float4 x6 = *(const float4*)(ip6 + e);
        float4 x7 = *(const float4*)(ip7 + e);
        acc[0] = fma4(w3, x0.w, fma4(w2, x0.z, fma4(w1, x0.y, fma4(w0, x0.x, acc[0]))));
        acc[1] = fma4(w3, x1.w, fma4(w2, x1.z, fma4(w1, x1.y, fma4(w0, x1.x, acc[1]))));
        acc[2] = fma4(w3, x2.w, fma4(w2, x2.z, fma4(w1, x2.y, fma4(w0, x2.x, acc[2]))));
        acc[3] = fma4(w3, x3.w, fma4(w2, x3.z, fma4(w1, x3.y, fma4(w0, x3.x, acc[3]))));
        acc[4] = fma4(w3, x4.w, fma4(w2, x4.z, fma4(w1, x4.y, fma4(w0, x4.x, acc[4]))));
        acc[5] = fma4(w3, x5.w, fma4(w2, x5.z, fma4(w1, x5.y, fma4(w0, x5.x, acc[5]))));
        acc[6] = fma4(w3, x6.w, fma4(w2, x6.z, fma4(w1, x6.y, fma4(w0, x6.x, acc[6]))));
        acc[7] = fma4(w3, x7.w, fma4(w2, x7.z, fma4(w1, x7.y, fma4(w0, x7.x, acc[7]))));
    }

    __shared__ float red[4][8][H_];   // 32 KB: [wave][row][h]
    #pragma unroll
    for (int r = 0; r < 8; ++r)
        *(float4*)&red[wid][r][4 * h4] = acc[r];
    __syncthreads();

    const int rr = tid >> 5;          // row 0..7
    const int hq = tid & 31;          // h4 group 0..31 (and +32)
    #pragma unroll
    for (int s = 0; s < 2; ++s) {
        const int hp = hq + 32 * s;   // h4 index 0..63
        float4 a0 = *(const float4*)&red[0][rr][4 * hp];
        float4 a1 = *(const float4*)&red[1][rr][4 * hp];
        float4 a2 = *(const float4*)&red[2][rr][4 * hp];
        float4 a3 = *(const float4*)&red[3][rr][4 * hp];
        float4 b4 = *(const float4*)(bias + 4 * hp);
        float4 v;
        v.x = fast_exp2(ARG_SCALE * (((a0.x + a1.x) + (a2.x + a3.x)) + b4.x));
        v.y = fast_exp2(ARG_SCALE * (((a0.y + a1.y) + (a2.y + a3.y)) + b4.y));
        v.z = fast_exp2(ARG_SCALE * (((a0.z + a1.z) + (a2.z + a3.z)) + b4.z));
        v.w = fast_exp2(ARG_SCALE * (((a0.w + a1.w) + (a2.w + a3.w)) + b4.w));
        *(float4*)(outp + (size_t)(row0 + rr) * H_ + 4 * hp) = v;
    }
}

// ---------------------------------------------------------------------------
// K2 v4: partial scores via exp-product. 128 threads; 32t x 32u tile; thread
// owns 4t x 2u. Grid (x: ut 0..4 | hs 0..1, y: tt, z: b).
//   sig = rcp(fma(Ee, Ed, 1))  ->  3 VALU / 1 trans per element
//   sc{hs}[t,u] = sum_{h in half} w[h]*sig; softmax combines halves with -2x.
// ---------------------------------------------------------------------------
__global__ __launch_bounds__(128) void score_kernel(
    const float* __restrict__ Ee, const float* __restrict__ Ed,
    const float* __restrict__ w_score,
    float* __restrict__ sc0, float* __restrict__ sc1)
{
    const int tid = threadIdx.x;
    const int ut = blockIdx.x % 5, hs = blockIdx.x / 5;
    const int tt = blockIdx.y, b = blockIdx.z;

    __shared__ float eld[32][PADH2];
    __shared__ float dld[32][PADH2];

    const int t0 = tt * 32, u0 = ut * 32;
    const int hoff = hs * 128;

    #pragma unroll
    for (int k = 0; k < 8; ++k) {
        int idx = tid + 128 * k;    // 0..1023
        int row = idx >> 5;         // 0..31
        int f4  = idx & 31;         // 0..31 float4s within the 128-h half
        *(float4*)&eld[row][4 * f4] =
            *(const float4*)(Ee + (size_t)(b * T_ + t0 + row) * H_ + hoff + 4 * f4);
        int du = u0 + row; if (du > U_ - 1) du = U_ - 1;
        *(float4*)&dld[row][4 * f4] =
            *(const float4*)(Ed + (size_t)(b * U_ + du) * H_ + hoff + 4 * f4);
    }
    __syncthreads();

    const int tx = tid & 15, ty = tid >> 4;       // ty 0..7
    const float* e0 = &eld[4 * ty + 0][0];
    const float* e1 = &eld[4 * ty + 1][0];
    const float* e2 = &eld[4 * ty + 2][0];
    const float* e3 = &eld[4 * ty + 3][0];
    const float* d0 = &dld[tx][0];
    const float* d1 = &dld[tx + 16][0];
    const float* wp = w_score + hoff;             // uniform -> s_load

    float4 z4 = {0.f, 0.f, 0.f, 0.f};
    float4 a00 = z4, a01 = z4, a10 = z4, a11 = z4;
    float4 a20 = z4, a21 = z4, a30 = z4, a31 = z4;

#define SIG(E, D) fast_rcp(fmaf((E), (D), 1.f))
#define ROW(A, EV, DV) \
    A.x = fmaf(w.x, SIG(EV.x, DV.x), A.x); \
    A.y = fmaf(w.y, SIG(EV.y, DV.y), A.y); \
    A.z = fmaf(w.z, SIG(EV.z, DV.z), A.z); \
    A.w = fmaf(w.w, SIG(EV.w, DV.w), A.w);

    #pragma unroll 4
    for (int h4 = 0; h4 < 32; ++h4) {
        float4 w  = ((const float4*)wp)[h4];
        float4 ea = *(const float4*)(e0 + 4 * h4);
        float4 eb = *(const float4*)(e1 + 4 * h4);
        float4 ec = *(const float4*)(e2 + 4 * h4);
        float4 ed = *(const float4*)(e3 + 4 * h4);
        float4 da = *(const float4*)(d0 + 4 * h4);
        float4 db = *(const float4*)(d1 + 4 * h4);
        ROW(a00, ea, da) ROW(a01, ea, db)
        ROW(a10, eb, da) ROW(a11, eb, db)
        ROW(a20, ec, da) ROW(a21, ec, db)
        ROW(a30, ed, da) ROW(a31, ed, db)
    }
#undef ROW
#undef SIG

    float s0[4], s1[4];
    s0[0] = (a00.x + a00.y) + (a00.z + a00.w);
    s0[1] = (a10.x + a10.y) + (a10.z + a10.w);
    s0[2] = (a20.x + a20.y) + (a20.z + a20.w);
    s0[3] = (a30.x + a30.y) + (a30.z + a30.w);
    s1[0] = (a01.x + a01.y) + (a01.z + a01.w);
    s1[1] = (a11.x + a11.y) + (a11.z + a11.w);
    s1[2] = (a21.x + a21.y) + (a21.z + a21.w);
    s1[3] = (a31.x + a31.y) + (a31.z + a31.w);

    float* sout = hs ? sc1 : sc0;
    const int ua = u0 + tx, ub = ua + 16;
    #pragma unroll
    for (int j = 0; j < 4; ++j) {
        const int t = t0 + 4 * ty + j;
        const size_t base = (size_t)(b * T_ + t) * U_;
        sout[base + ua] = s0[j];
        if (ub < U_) sout[base + ub] = s1[j];
    }
}

// ---------------------------------------------------------------------------
// K3: softmax over U=150 of z = -2*(sc0+sc1). One wave per row; writes d_out.
// ---------------------------------------------------------------------------
__global__ __launch_bounds__(256) void softmax_kernel(
    const float* __restrict__ sc0, const float* __restrict__ sc1,
    float* __restrict__ out)
{
    const int tid  = threadIdx.x;
    const int wave = tid >> 6, lane = tid & 63;
    const int row  = blockIdx.x * 4 + wave;       // 0..3199
    const size_t base = (size_t)row * U_;

    float z0 = -2.f * (sc0[base + lane]      + sc1[base + lane]);
    float z1 = -2.f * (sc0[base + lane + 64] + sc1[base + lane + 64]);
    const bool v2 = (lane + 128) < U_;
    float z2 = v2 ? -2.f * (sc0[base + lane + 128] + sc1[base + lane + 128])
                  : -INFINITY;

    float m = fmaxf(fmaxf(z0, z1), z2);
    #pragma unroll
    for (int off = 32; off > 0; off >>= 1) m = fmaxf(m, __shfl_xor(m, off));

    float p0 = fast_exp2((z0 - m) * LOG2E_F);
    float p1 = fast_exp2((z1 - m) * LOG2E_F);
    float p2 = v2 ? fast_exp2((z2 - m) * LOG2E_F) : 0.f;

    float s = p0 + p1 + p2;
    #pragma unroll
    for (int off = 32; off > 0; off >>= 1) s += __shfl_xor(s, off);

    const float inv = 1.0f / s;   // IEEE divide for accuracy
    out[base + lane]      = p0 * inv;
    out[base + lane + 64] = p1 * inv;
    if (v2) out[base + lane + 128] = p2 * inv;
}

// ---------------------------------------------------------------------------
extern "C" void kernel_launch(void* const* d_in, const int* in_sizes, int n_in,
                              void* d_out, int out_size, void* d_ws, size_t ws_size,
                              hipStream_t stream) {
    const float* enc     = (const float*)d_in[0];
    const float* dec     = (const float*)d_in[1];
    const float* W_enc   = (const float*)d_in[2];
    const float* b_enc   = (const float*)d_in[3];
    const float* W_dec   = (const float*)d_in[4];
    const float* b_dec   = (const float*)d_in[5];
    const float* w_score = (const float*)d_in[6];
    // d_in[7] = b_score: cancels in softmax, unused.

    float* ws = (float*)d_ws;
    float* Ee  = ws;                    // [3200,256] exp2(c*(enc_proj))
    float* Ed  = Ee + 819200;           // [600,256]  exp2(c*(dec_proj))
    float* sc0 = Ed + 153600;           // [3200,150] partial score, h 0..127
    float* sc1 = sc0 + 480000;          // [3200,150] partial score, h 128..255
    float* out = (float*)d_out;

    proj_exp_kernel<<<475, 256, 0, stream>>>(enc, dec, W_enc, b_enc, W_dec, b_dec, Ee, Ed);
    score_kernel<<<dim3(10, 25, 4), 128, 0, stream>>>(Ee, Ed, w_score, sc0, sc1);
    softmax_kernel<<<800, 256, 0, stream>>>(sc0, sc1, out);
}